// Round 2
// baseline (871.751 us; speedup 1.0000x reference)
//
#include <hip/hip_runtime.h>
#include <stdint.h>

#define NLEVELS 16
#define BLOCK 256

__global__ __launch_bounds__(BLOCK, 8) void hashgrid_encode_kernel(
    const float* __restrict__ xyz,
    const float* __restrict__ emb,
    const float* __restrict__ minv,
    const float* __restrict__ maxv,
    float* __restrict__ out,
    int B)
{
    constexpr int RES[NLEVELS] = {16, 22, 30, 42, 58, 80, 111, 154,
                                  212, 294, 406, 561, 776, 1072, 1482, 2048};
    // half-transpose buffer: 16 feature rows x (BLOCK+1) points
    // stride 257 (mod 32 == 1) -> 2-way-max bank aliasing on both sides (free)
    __shared__ float s[16][BLOCK + 1];

    const int t = threadIdx.x;
    const int pt = blockIdx.x * BLOCK + t;

    const float mn0 = minv[0], mn1 = minv[1], mn2 = minv[2];
    const float inv0 = 1.0f / (maxv[0] - mn0);
    const float inv1 = 1.0f / (maxv[1] - mn1);
    const float inv2 = 1.0f / (maxv[2] - mn2);

    float nx = 0.0f, ny = 0.0f, nz = 0.0f;
    bool valid = false;
    if (pt < B) {
        const float x = xyz[3 * pt + 0];
        const float y = xyz[3 * pt + 1];
        const float z = xyz[3 * pt + 2];
        nx = (x - mn0) * inv0;
        ny = (y - mn1) * inv1;
        nz = (z - mn2) * inv2;
        valid = (nx >= 0.0f) && (nx <= 1.0f) &&
                (ny >= 0.0f) && (ny <= 1.0f) &&
                (nz >= 0.0f) && (nz <= 1.0f);
    }

    const size_t chunk = (size_t)blockIdx.x * (BLOCK * 32);

    #pragma unroll
    for (int half = 0; half < 2; ++half) {
        if (half) __syncthreads();   // previous half's reads done before overwrite

        #pragma unroll
        for (int l8 = 0; l8 < 8; ++l8) {
            const int l = half * 8 + l8;
            const int r = RES[l];
            const float rm1 = (float)(r - 1);

            const float px = nx * rm1;
            const float py = ny * rm1;
            const float pz = nz * rm1;

            int fx = (int)floorf(px); fx = min(max(fx, 0), r - 2);
            int fy = (int)floorf(py); fy = min(max(fy, 0), r - 2);
            int fz = (int)floorf(pz); fz = min(max(fz, 0), r - 2);

            const float fracx = px - (float)fx;
            const float fracy = py - (float)fy;
            const float fracz = pz - (float)fz;

            // per-axis hashes for both corner coords (primes[0] == 1)
            const uint32_t hx0 = (uint32_t)fx;
            const uint32_t hx1 = hx0 + 1u;
            const uint32_t hy0 = (uint32_t)fy * 2654435761u;
            const uint32_t hy1 = hy0 + 2654435761u;
            const uint32_t hz0 = (uint32_t)fz * 805459861u;
            const uint32_t hz1 = hz0 + 805459861u;

            const uint32_t basei = (uint32_t)l << 19;   // l * 524288

            const float wx1 = fracx, wx0 = 1.0f - fracx;
            const float wy1 = fracy, wy0 = 1.0f - fracy;
            const float wz1 = fracz, wz0 = 1.0f - fracz;

            float acc0 = 0.0f, acc1 = 0.0f;
            #pragma unroll
            for (int c = 0; c < 8; ++c) {
                const uint32_t h = ((c & 1) ? hx1 : hx0) ^
                                   ((c & 2) ? hy1 : hy0) ^
                                   ((c & 4) ? hz1 : hz0);
                const uint32_t idx = basei + (h & 0x7FFFFu);
                const float2 f = *reinterpret_cast<const float2*>(emb + ((size_t)idx << 1));
                const float w = ((c & 1) ? wx1 : wx0) *
                                ((c & 2) ? wy1 : wy0) *
                                ((c & 4) ? wz1 : wz0);
                acc0 = fmaf(w, f.x, acc0);
                acc1 = fmaf(w, f.y, acc1);
            }
            s[2 * l8 + 0][t] = valid ? acc0 : 0.0f;
            s[2 * l8 + 1][t] = valid ? acc1 : 0.0f;
        }

        __syncthreads();

        // coalesced writeout of this half's 16 features for the block's points
        #pragma unroll
        for (int k = 0; k < 16; ++k) {
            const int flat = k * BLOCK + t;       // 0 .. BLOCK*16-1
            const int p = flat >> 4;              // point within block
            const int c = flat & 15;              // feature within half
            if (blockIdx.x * BLOCK + p < B) {
                out[chunk + (size_t)p * 32 + half * 16 + c] = s[c][p];
            }
        }
    }
}

extern "C" void kernel_launch(void* const* d_in, const int* in_sizes, int n_in,
                              void* d_out, int out_size, void* d_ws, size_t ws_size,
                              hipStream_t stream) {
    const float* xyz = (const float*)d_in[0];
    const float* emb = (const float*)d_in[1];
    const float* mn  = (const float*)d_in[2];
    const float* mx  = (const float*)d_in[3];
    float* out = (float*)d_out;

    const int B = in_sizes[0] / 3;
    const int blocks = (B + BLOCK - 1) / BLOCK;

    hipLaunchKernelGGL(hashgrid_encode_kernel, dim3(blocks), dim3(BLOCK), 0, stream,
                       xyz, emb, mn, mx, out, B);
}

// Round 3
// 442.010 us; speedup vs baseline: 1.9722x; 1.9722x over previous
//
#include <hip/hip_runtime.h>
#include <stdint.h>

#define NLEVELS 16
#define BLOCK 256

__device__ __constant__ const int RES_C[NLEVELS] = {16, 22, 30, 42, 58, 80, 111, 154,
                                                    212, 294, 406, 561, 776, 1072, 1482, 2048};

// ---------------- level-phased gather kernels ----------------
// Computes levels [L0, L1) for every point, writing contiguous per-level slabs
// ws2[l*B + p] = (f0, f1)  (zeroed when point outside the grid).
template <int L0, int L1>
__global__ __launch_bounds__(BLOCK) void level_gather_kernel(
    const float* __restrict__ xyz,
    const float* __restrict__ emb,
    const float* __restrict__ minv,
    const float* __restrict__ maxv,
    float2* __restrict__ ws2,
    int B)
{
    constexpr int RES[NLEVELS] = {16, 22, 30, 42, 58, 80, 111, 154,
                                  212, 294, 406, 561, 776, 1072, 1482, 2048};
    const int pt = blockIdx.x * BLOCK + threadIdx.x;
    if (pt >= B) return;

    const float mn0 = minv[0], mn1 = minv[1], mn2 = minv[2];
    const float inv0 = 1.0f / (maxv[0] - mn0);
    const float inv1 = 1.0f / (maxv[1] - mn1);
    const float inv2 = 1.0f / (maxv[2] - mn2);

    const float x = xyz[3 * pt + 0];
    const float y = xyz[3 * pt + 1];
    const float z = xyz[3 * pt + 2];
    const float nx = (x - mn0) * inv0;
    const float ny = (y - mn1) * inv1;
    const float nz = (z - mn2) * inv2;
    const bool valid = (nx >= 0.0f) && (nx <= 1.0f) &&
                       (ny >= 0.0f) && (ny <= 1.0f) &&
                       (nz >= 0.0f) && (nz <= 1.0f);

    #pragma unroll
    for (int l = L0; l < L1; ++l) {
        const int r = RES[l];
        const float rm1 = (float)(r - 1);

        const float px = nx * rm1;
        const float py = ny * rm1;
        const float pz = nz * rm1;

        int fx = (int)floorf(px); fx = min(max(fx, 0), r - 2);
        int fy = (int)floorf(py); fy = min(max(fy, 0), r - 2);
        int fz = (int)floorf(pz); fz = min(max(fz, 0), r - 2);

        const float fracx = px - (float)fx;
        const float fracy = py - (float)fy;
        const float fracz = pz - (float)fz;

        // per-axis hashes for both corner coords (primes[0] == 1)
        const uint32_t hx0 = (uint32_t)fx;
        const uint32_t hx1 = hx0 + 1u;
        const uint32_t hy0 = (uint32_t)fy * 2654435761u;
        const uint32_t hy1 = hy0 + 2654435761u;
        const uint32_t hz0 = (uint32_t)fz * 805459861u;
        const uint32_t hz1 = hz0 + 805459861u;

        const uint32_t basei = (uint32_t)l << 19;   // l * 524288

        const float wx1 = fracx, wx0 = 1.0f - fracx;
        const float wy1 = fracy, wy0 = 1.0f - fracy;
        const float wz1 = fracz, wz0 = 1.0f - fracz;

        float acc0 = 0.0f, acc1 = 0.0f;
        #pragma unroll
        for (int c = 0; c < 8; ++c) {
            const uint32_t h = ((c & 1) ? hx1 : hx0) ^
                               ((c & 2) ? hy1 : hy0) ^
                               ((c & 4) ? hz1 : hz0);
            const uint32_t idx = basei + (h & 0x7FFFFu);
            const float2 f = *reinterpret_cast<const float2*>(emb + ((size_t)idx << 1));
            const float w = ((c & 1) ? wx1 : wx0) *
                            ((c & 2) ? wy1 : wy0) *
                            ((c & 4) ? wz1 : wz0);
            acc0 = fmaf(w, f.x, acc0);
            acc1 = fmaf(w, f.y, acc1);
        }
        float2 o;
        o.x = valid ? acc0 : 0.0f;
        o.y = valid ? acc1 : 0.0f;
        ws2[(size_t)l * B + pt] = o;
    }
}

// ---------------- final transpose: ws[16][B][2] -> out[B][32] ----------------
__global__ __launch_bounds__(BLOCK) void transpose_kernel(
    const float2* __restrict__ ws2,
    float* __restrict__ out,
    int B)
{
    __shared__ float s[32][BLOCK + 1];   // stride 257: at worst 2-way bank alias (free)
    const int t = threadIdx.x;
    const int pt = blockIdx.x * BLOCK + t;

    #pragma unroll
    for (int l = 0; l < NLEVELS; ++l) {
        float2 v = make_float2(0.0f, 0.0f);
        if (pt < B) v = ws2[(size_t)l * B + pt];
        s[2 * l + 0][t] = v.x;
        s[2 * l + 1][t] = v.y;
    }
    __syncthreads();

    const size_t chunk = (size_t)blockIdx.x * (BLOCK * 32);
    const size_t total = (size_t)B * 32;
    #pragma unroll
    for (int k = 0; k < 32; ++k) {
        const int flat = k * BLOCK + t;
        const int p = flat >> 5;
        const int c = flat & 31;
        const size_t g = chunk + (size_t)flat;
        if (g < total) out[g] = s[c][p];
    }
}

// ---------------- fallback: single fused kernel (R0, 605 us) ----------------
__global__ __launch_bounds__(BLOCK) void hashgrid_fused_kernel(
    const float* __restrict__ xyz,
    const float* __restrict__ emb,
    const float* __restrict__ minv,
    const float* __restrict__ maxv,
    float* __restrict__ out,
    int B)
{
    constexpr int RES[NLEVELS] = {16, 22, 30, 42, 58, 80, 111, 154,
                                  212, 294, 406, 561, 776, 1072, 1482, 2048};
    __shared__ float s[32][BLOCK + 1];

    const int t = threadIdx.x;
    const int pt = blockIdx.x * BLOCK + t;

    const float mn0 = minv[0], mn1 = minv[1], mn2 = minv[2];
    const float inv0 = 1.0f / (maxv[0] - mn0);
    const float inv1 = 1.0f / (maxv[1] - mn1);
    const float inv2 = 1.0f / (maxv[2] - mn2);

    float nx = 0.0f, ny = 0.0f, nz = 0.0f;
    bool valid = false;
    if (pt < B) {
        const float x = xyz[3 * pt + 0];
        const float y = xyz[3 * pt + 1];
        const float z = xyz[3 * pt + 2];
        nx = (x - mn0) * inv0;
        ny = (y - mn1) * inv1;
        nz = (z - mn2) * inv2;
        valid = (nx >= 0.0f) && (nx <= 1.0f) &&
                (ny >= 0.0f) && (ny <= 1.0f) &&
                (nz >= 0.0f) && (nz <= 1.0f);
    }

    #pragma unroll
    for (int l = 0; l < NLEVELS; ++l) {
        const int r = RES[l];
        const float rm1 = (float)(r - 1);
        const float px = nx * rm1, py = ny * rm1, pz = nz * rm1;
        int fx = (int)floorf(px); fx = min(max(fx, 0), r - 2);
        int fy = (int)floorf(py); fy = min(max(fy, 0), r - 2);
        int fz = (int)floorf(pz); fz = min(max(fz, 0), r - 2);
        const float fracx = px - (float)fx;
        const float fracy = py - (float)fy;
        const float fracz = pz - (float)fz;
        const uint32_t hx0 = (uint32_t)fx, hx1 = hx0 + 1u;
        const uint32_t hy0 = (uint32_t)fy * 2654435761u, hy1 = hy0 + 2654435761u;
        const uint32_t hz0 = (uint32_t)fz * 805459861u,  hz1 = hz0 + 805459861u;
        const uint32_t basei = (uint32_t)l << 19;
        const float wx1 = fracx, wx0 = 1.0f - fracx;
        const float wy1 = fracy, wy0 = 1.0f - fracy;
        const float wz1 = fracz, wz0 = 1.0f - fracz;
        float acc0 = 0.0f, acc1 = 0.0f;
        #pragma unroll
        for (int c = 0; c < 8; ++c) {
            const uint32_t h = ((c & 1) ? hx1 : hx0) ^
                               ((c & 2) ? hy1 : hy0) ^
                               ((c & 4) ? hz1 : hz0);
            const uint32_t idx = basei + (h & 0x7FFFFu);
            const float2 f = *reinterpret_cast<const float2*>(emb + ((size_t)idx << 1));
            const float w = ((c & 1) ? wx1 : wx0) *
                            ((c & 2) ? wy1 : wy0) *
                            ((c & 4) ? wz1 : wz0);
            acc0 = fmaf(w, f.x, acc0);
            acc1 = fmaf(w, f.y, acc1);
        }
        s[2 * l + 0][t] = valid ? acc0 : 0.0f;
        s[2 * l + 1][t] = valid ? acc1 : 0.0f;
    }
    __syncthreads();
    const size_t chunk = (size_t)blockIdx.x * (BLOCK * 32);
    const size_t total = (size_t)B * 32;
    #pragma unroll
    for (int k = 0; k < 32; ++k) {
        const int flat = k * BLOCK + t;
        const int p = flat >> 5;
        const int c = flat & 31;
        const size_t g = chunk + (size_t)flat;
        if (g < total) out[g] = s[c][p];
    }
}

extern "C" void kernel_launch(void* const* d_in, const int* in_sizes, int n_in,
                              void* d_out, int out_size, void* d_ws, size_t ws_size,
                              hipStream_t stream) {
    const float* xyz = (const float*)d_in[0];
    const float* emb = (const float*)d_in[1];
    const float* mn  = (const float*)d_in[2];
    const float* mx  = (const float*)d_in[3];
    float* out = (float*)d_out;

    const int B = in_sizes[0] / 3;
    const int blocks = (B + BLOCK - 1) / BLOCK;
    const size_t ws_needed = (size_t)NLEVELS * (size_t)B * 2 * sizeof(float);

    if (ws_size >= ws_needed) {
        float2* ws2 = (float2*)d_ws;
        // levels 0-4 fused: combined table working set ~2.5 MB (fits L2 easily)
        hipLaunchKernelGGL((level_gather_kernel<0, 5>), dim3(blocks), dim3(BLOCK), 0, stream,
                           xyz, emb, mn, mx, ws2, B);
        // levels 5-15: one kernel each; the active 4 MB table slice ~= one XCD L2
        #define LVL(L) hipLaunchKernelGGL((level_gather_kernel<L, L + 1>), dim3(blocks), dim3(BLOCK), 0, stream, xyz, emb, mn, mx, ws2, B)
        LVL(5); LVL(6); LVL(7); LVL(8); LVL(9); LVL(10);
        LVL(11); LVL(12); LVL(13); LVL(14); LVL(15);
        #undef LVL
        hipLaunchKernelGGL(transpose_kernel, dim3(blocks), dim3(BLOCK), 0, stream,
                           ws2, out, B);
    } else {
        hipLaunchKernelGGL(hashgrid_fused_kernel, dim3(blocks), dim3(BLOCK), 0, stream,
                           xyz, emb, mn, mx, out, B);
    }
}

// Round 4
// 426.672 us; speedup vs baseline: 2.0431x; 1.0359x over previous
//
#include <hip/hip_runtime.h>
#include <stdint.h>

#define NLEVELS 16
#define BLOCK 256

// ---------------- shared helpers ----------------

struct PointCtx {
    float nx, ny, nz;
    bool valid;
};

__device__ __forceinline__ PointCtx make_ctx(const float* __restrict__ xyz, int pt, int B,
                                             float mn0, float mn1, float mn2,
                                             float inv0, float inv1, float inv2)
{
    PointCtx P;
    P.nx = P.ny = P.nz = 0.0f;
    P.valid = false;
    if (pt < B) {
        const float x = xyz[3 * pt + 0];
        const float y = xyz[3 * pt + 1];
        const float z = xyz[3 * pt + 2];
        P.nx = (x - mn0) * inv0;
        P.ny = (y - mn1) * inv1;
        P.nz = (z - mn2) * inv2;
        P.valid = (P.nx >= 0.0f) && (P.nx <= 1.0f) &&
                  (P.ny >= 0.0f) && (P.ny <= 1.0f) &&
                  (P.nz >= 0.0f) && (P.nz <= 1.0f);
    }
    return P;
}

// Trilinear hash-grid lookup for one (point, level), with x-corner-pair
// vectorization: primes[0]==1 means corners (fx, fx+1) map to table entries
// {i, i^1} when fx is even -> one aligned float4 load covers both corners.
__device__ __forceinline__ float2 level_encode(const PointCtx& P,
                                               const float* __restrict__ emb,
                                               int l, int r)
{
    const float rm1 = (float)(r - 1);
    const float px = P.nx * rm1;
    const float py = P.ny * rm1;
    const float pz = P.nz * rm1;

    int fx = (int)floorf(px); fx = min(max(fx, 0), r - 2);
    int fy = (int)floorf(py); fy = min(max(fy, 0), r - 2);
    int fz = (int)floorf(pz); fz = min(max(fz, 0), r - 2);

    const float fracx = px - (float)fx;
    const float fracy = py - (float)fy;
    const float fracz = pz - (float)fz;

    const uint32_t hx0 = (uint32_t)fx;
    const uint32_t hy0 = (uint32_t)fy * 2654435761u;
    const uint32_t hy1 = hy0 + 2654435761u;
    const uint32_t hz0 = (uint32_t)fz * 805459861u;
    const uint32_t hz1 = hz0 + 805459861u;

    const uint32_t basei = (uint32_t)l << 19;       // l * 524288
    const bool even = (fx & 1) == 0;

    const float wx1 = fracx, wx0 = 1.0f - fracx;
    const float wy1 = fracy, wy0 = 1.0f - fracy;
    const float wz1 = fracz, wz0 = 1.0f - fracz;

    float acc0 = 0.0f, acc1 = 0.0f;
    #pragma unroll
    for (int yz = 0; yz < 4; ++yz) {
        const uint32_t rest = ((yz & 1) ? hy1 : hy0) ^ ((yz & 2) ? hz1 : hz0);
        const float wyz = ((yz & 1) ? wy1 : wy0) * ((yz & 2) ? wz1 : wz0);
        const uint32_t i0 = (hx0 ^ rest) & 0x7FFFFu;

        float2 c0, c1;
        if (even) {
            // {i0, i0^1} = aligned consecutive pair; 16B aligned load
            const float4 f = *reinterpret_cast<const float4*>(
                emb + ((size_t)(basei + (i0 & ~1u)) << 1));
            const bool lo = (i0 & 1u) == 0u;
            c0 = lo ? make_float2(f.x, f.y) : make_float2(f.z, f.w);
            c1 = lo ? make_float2(f.z, f.w) : make_float2(f.x, f.y);
        } else {
            const uint32_t i1 = ((hx0 + 1u) ^ rest) & 0x7FFFFu;
            c0 = *reinterpret_cast<const float2*>(emb + ((size_t)(basei + i0) << 1));
            c1 = *reinterpret_cast<const float2*>(emb + ((size_t)(basei + i1) << 1));
        }
        acc0 += wyz * (wx0 * c0.x + wx1 * c1.x);
        acc1 += wyz * (wx0 * c0.y + wx1 * c1.y);
    }
    float2 o;
    o.x = P.valid ? acc0 : 0.0f;
    o.y = P.valid ? acc1 : 0.0f;
    return o;
}

// ---------------- levels 0-4 fused (working set ~2.5 MB, L2-resident) ----------------
__global__ __launch_bounds__(BLOCK, 6) void level_gather_low_kernel(
    const float* __restrict__ xyz,
    const float* __restrict__ emb,
    const float* __restrict__ minv,
    const float* __restrict__ maxv,
    float2* __restrict__ ws2,
    int B)
{
    constexpr int RES[5] = {16, 22, 30, 42, 58};
    const int pt = blockIdx.x * BLOCK + threadIdx.x;
    if (pt >= B) return;

    const float mn0 = minv[0], mn1 = minv[1], mn2 = minv[2];
    const float inv0 = 1.0f / (maxv[0] - mn0);
    const float inv1 = 1.0f / (maxv[1] - mn1);
    const float inv2 = 1.0f / (maxv[2] - mn2);

    const PointCtx P = make_ctx(xyz, pt, B, mn0, mn1, mn2, inv0, inv1, inv2);

    #pragma unroll
    for (int l = 0; l < 5; ++l) {
        ws2[(size_t)l * B + pt] = level_encode(P, emb, l, RES[l]);
    }
}

// ---------------- one level, 2 points per thread (levels 5-15) ----------------
template <int L, int R>
__global__ __launch_bounds__(BLOCK, 6) void level_gather_2pt_kernel(
    const float* __restrict__ xyz,
    const float* __restrict__ emb,
    const float* __restrict__ minv,
    const float* __restrict__ maxv,
    float2* __restrict__ ws2,
    int B)
{
    const int t = threadIdx.x;
    const int p0 = blockIdx.x * (2 * BLOCK) + t;
    const int p1 = p0 + BLOCK;

    const float mn0 = minv[0], mn1 = minv[1], mn2 = minv[2];
    const float inv0 = 1.0f / (maxv[0] - mn0);
    const float inv1 = 1.0f / (maxv[1] - mn1);
    const float inv2 = 1.0f / (maxv[2] - mn2);

    const PointCtx P0 = make_ctx(xyz, p0, B, mn0, mn1, mn2, inv0, inv1, inv2);
    const PointCtx P1 = make_ctx(xyz, p1, B, mn0, mn1, mn2, inv0, inv1, inv2);

    const float2 o0 = level_encode(P0, emb, L, R);
    const float2 o1 = level_encode(P1, emb, L, R);

    if (p0 < B) ws2[(size_t)L * B + p0] = o0;
    if (p1 < B) ws2[(size_t)L * B + p1] = o1;
}

// ---------------- final transpose: ws[16][B][2] -> out[B][32] ----------------
__global__ __launch_bounds__(BLOCK) void transpose_kernel(
    const float2* __restrict__ ws2,
    float* __restrict__ out,
    int B)
{
    __shared__ float s[32][BLOCK + 1];   // stride 257: worst 2-way bank alias (free)
    const int t = threadIdx.x;
    const int pt = blockIdx.x * BLOCK + t;

    #pragma unroll
    for (int l = 0; l < NLEVELS; ++l) {
        float2 v = make_float2(0.0f, 0.0f);
        if (pt < B) v = ws2[(size_t)l * B + pt];
        s[2 * l + 0][t] = v.x;
        s[2 * l + 1][t] = v.y;
    }
    __syncthreads();

    const size_t chunk = (size_t)blockIdx.x * (BLOCK * 32);
    const size_t total = (size_t)B * 32;
    #pragma unroll
    for (int k = 0; k < 32; ++k) {
        const int flat = k * BLOCK + t;
        const int p = flat >> 5;
        const int c = flat & 31;
        const size_t g = chunk + (size_t)flat;
        if (g < total) out[g] = s[c][p];
    }
}

// ---------------- fallback: single fused kernel (R0 structure) ----------------
__global__ __launch_bounds__(BLOCK) void hashgrid_fused_kernel(
    const float* __restrict__ xyz,
    const float* __restrict__ emb,
    const float* __restrict__ minv,
    const float* __restrict__ maxv,
    float* __restrict__ out,
    int B)
{
    constexpr int RES[NLEVELS] = {16, 22, 30, 42, 58, 80, 111, 154,
                                  212, 294, 406, 561, 776, 1072, 1482, 2048};
    __shared__ float s[32][BLOCK + 1];
    const int t = threadIdx.x;
    const int pt = blockIdx.x * BLOCK + t;

    const float mn0 = minv[0], mn1 = minv[1], mn2 = minv[2];
    const float inv0 = 1.0f / (maxv[0] - mn0);
    const float inv1 = 1.0f / (maxv[1] - mn1);
    const float inv2 = 1.0f / (maxv[2] - mn2);

    const PointCtx P = make_ctx(xyz, pt, B, mn0, mn1, mn2, inv0, inv1, inv2);

    #pragma unroll
    for (int l = 0; l < NLEVELS; ++l) {
        const float2 o = level_encode(P, emb, l, RES[l]);
        s[2 * l + 0][t] = o.x;
        s[2 * l + 1][t] = o.y;
    }
    __syncthreads();
    const size_t chunk = (size_t)blockIdx.x * (BLOCK * 32);
    const size_t total = (size_t)B * 32;
    #pragma unroll
    for (int k = 0; k < 32; ++k) {
        const int flat = k * BLOCK + t;
        const int p = flat >> 5;
        const int c = flat & 31;
        const size_t g = chunk + (size_t)flat;
        if (g < total) out[g] = s[c][p];
    }
}

extern "C" void kernel_launch(void* const* d_in, const int* in_sizes, int n_in,
                              void* d_out, int out_size, void* d_ws, size_t ws_size,
                              hipStream_t stream) {
    const float* xyz = (const float*)d_in[0];
    const float* emb = (const float*)d_in[1];
    const float* mn  = (const float*)d_in[2];
    const float* mx  = (const float*)d_in[3];
    float* out = (float*)d_out;

    const int B = in_sizes[0] / 3;
    const int blocks1 = (B + BLOCK - 1) / BLOCK;
    const int blocks2 = (B + 2 * BLOCK - 1) / (2 * BLOCK);
    const size_t ws_needed = (size_t)NLEVELS * (size_t)B * 2 * sizeof(float);

    if (ws_size >= ws_needed) {
        float2* ws2 = (float2*)d_ws;
        hipLaunchKernelGGL(level_gather_low_kernel, dim3(blocks1), dim3(BLOCK), 0, stream,
                           xyz, emb, mn, mx, ws2, B);
        #define LVL(L, R) hipLaunchKernelGGL((level_gather_2pt_kernel<L, R>), dim3(blocks2), dim3(BLOCK), 0, stream, xyz, emb, mn, mx, ws2, B)
        LVL(5, 80);  LVL(6, 111);  LVL(7, 154);  LVL(8, 212);
        LVL(9, 294); LVL(10, 406); LVL(11, 561); LVL(12, 776);
        LVL(13, 1072); LVL(14, 1482); LVL(15, 2048);
        #undef LVL
        hipLaunchKernelGGL(transpose_kernel, dim3(blocks1), dim3(BLOCK), 0, stream,
                           ws2, out, B);
    } else {
        hipLaunchKernelGGL(hashgrid_fused_kernel, dim3(blocks1), dim3(BLOCK), 0, stream,
                           xyz, emb, mn, mx, out, B);
    }
}